// Round 12
// baseline (134.118 us; speedup 1.0000x reference)
//
#include <hip/hip_runtime.h>
#include <hip/hip_bf16.h>

// Forbid FMA contraction in ALL device code below: the kNN ranking must
// bit-match the reference's uncontracted fp32 expression
//   pd[i,j] = 2*inner(i,j) - xx[i] - xx[j]
// (rounds 4/6/8/10/11 passed uncontracted; round 5 regressed when the
// compiler fused 2*inner-xxi into v_fma_f32). fmaf() in linear_kernel is
// unaffected by this pragma.
#pragma clang fp contract(off)

// B=4, N=4096, C=128, K=32. All fp32. top-K LARGEST pd, tie -> lowest index.
// Round 12: Q=4 queries per block. Each thread loads its 16 candidates'
// (px,py,pz,xxj) ONCE and computes pd for 4 queries from registers --
// r11 profile showed VALU-issue-bound with per-candidate load addressing
// (4 scalar loads x 64-bit addr arith, redone per query) as the biggest
// slice. Selection machinery per query is the r11-proven code verbatim
// (thread-max histogram -> suffix scan -> conservative edge -> survivor
// pass -> 64-lane bitonic refinement). __launch_bounds__(256,4) pins
// VGPR<=128 so occupancy stays at the measured ~50% band.

constexpr int NB   = 4;
constexpr int NP   = 4096;
constexpr int NC   = 128;
constexpr int NK   = 32;
constexpr int NT   = 256;
constexpr int PERT = NP / NT; // 16
constexpr int NQ   = 4;       // queries per block

__device__ __forceinline__ unsigned skew(unsigned d) { return d + (d >> 5); }

// ---------------------------------------------------------------------------
// Kernel P: xxw[b*NP+j] = xx_j, bit-identical to the reference's
// uncontracted (x*x + y*y) + z*z.
// ---------------------------------------------------------------------------
__global__ __launch_bounds__(NT) void precompute_kernel(
    const float* __restrict__ xyz,    // [B,3,N]
    float* __restrict__ xxw)          // [B*NP]
{
    const int g = blockIdx.x * NT + threadIdx.x;   // 0 .. B*NP-1
    const int b = g >> 12;
    const int j = g & (NP - 1);
    const float* xb = xyz + (size_t)b * 3 * NP;
    const float x = xb[j];
    const float y = xb[NP + j];
    const float z = xb[2 * NP + j];
    xxw[g] = (x * x + y * y) + z * z;              // each op rounded (no FMA)
}

// ---------------------------------------------------------------------------
// Kernel A: 4 queries per block; kNN (prefilter select) + mean pool.
// ---------------------------------------------------------------------------
template <bool USE_WS>
__global__ __launch_bounds__(NT, 4) void knn_pool_kernel(
    const float* __restrict__ xyz,    // [B,3,N]
    const float* __restrict__ xxw,    // [B*NP] (USE_WS only)
    const float* __restrict__ feats,  // [B,N,C]
    float* __restrict__ pooled)       // [B*N, C] (d_out, fp32 temp)
{
    const int blk  = blockIdx.x;          // 0 .. NB*NP/NQ-1
    const int b    = blk >> 10;           // NP/NQ = 1024 blocks per batch
    const int i0   = (blk & 1023) * NQ;   // first query index
    const int t    = threadIdx.x;
    const int lane = t & 63;
    const int wid  = t >> 6;

    const float* xb  = xyz + (size_t)b * 3 * NP;
    const float* xxb = USE_WS ? (xxw + ((size_t)b << 12)) : nullptr;

    // query coords (block-uniform)
    float qx[NQ], qy[NQ], qz[NQ], xxi[NQ];
    #pragma unroll
    for (int q = 0; q < NQ; ++q) {
        const int i = i0 + q;
        qx[q] = xb[i];
        qy[q] = xb[NP + i];
        qz[q] = xb[2 * NP + i];
        if constexpr (USE_WS) xxi[q] = xxb[i];
        else                  xxi[q] = (qx[q]*qx[q] + qy[q]*qy[q]) + qz[q]*qz[q];
    }

    // main loop: load each candidate ONCE, compute pd for all 4 queries
    float pdv[NQ][PERT];
    float tmax[NQ];
    #pragma unroll
    for (int q = 0; q < NQ; ++q) tmax[q] = -3.0e38f;

    #pragma unroll
    for (int m = 0; m < PERT; ++m) {
        const int j = m * NT + t;
        const float px = xb[j];
        const float py = xb[NP + j];
        const float pz = xb[2 * NP + j];
        float xxj;
        if constexpr (USE_WS) xxj = xxb[j];
        else                  xxj = (px * px + py * py) + pz * pz;
        #pragma unroll
        for (int q = 0; q < NQ; ++q) {
            const float inner = (qx[q] * px + qy[q] * py) + qz[q] * pz;
            const float pd    = (2.0f * inner - xxi[q]) - xxj;
            pdv[q][m] = pd;
            tmax[q] = fmaxf(tmax[q], pd);
        }
    }

    // bins of the 4 thread-maxima (monotone uniformized map, as r11)
    unsigned dgmax[NQ];
    #pragma unroll
    for (int q = 0; q < NQ; ++q) {
        const float qm = fmaxf(tmax[q] + 24.0f, 0.0f) * 67108864.0f; // *2^26
        dgmax[q] = min(((unsigned)qm) >> 19, 3072u);                  // 0..3072
    }

    __shared__ unsigned s_hist[3200];   // 3073 skewed bins (12.8 KiB)
    __shared__ int      s_sel[NK];
    __shared__ int      s_sj[256];
    __shared__ unsigned s_sk[256];
    __shared__ unsigned s_G[NT];
    __shared__ unsigned s_wtot[4];
    __shared__ unsigned s_scnt, s_digit;
    __shared__ float    s_red[NT];

    const float* fb = feats + (size_t)b * NP * NC;

    #pragma unroll
    for (int q = 0; q < NQ; ++q) {
        // ---- per-query selection (r11 machinery, verbatim) ----
        if (t == 0) { s_scnt = 0; s_digit = 0; }
        if (t < NK) s_sel[t] = 0;       // defensive: never leave garbage
        {   // wide zeroing: 800 uint4 across 256 threads
            uint4* hz = (uint4*)s_hist;
            for (int z = t; z < 800; z += NT) hz[z] = make_uint4(0u,0u,0u,0u);
        }
        __syncthreads();

        atomicAdd(&s_hist[skew(dgmax[q])], 1u);
        __syncthreads();

        // block suffix scan: G[t] = # maxima with bin >= 16*t
        unsigned h[16];
        unsigned hsum = 0;
        #pragma unroll
        for (int e = 0; e < 16; ++e) {
            const unsigned bin = (unsigned)(t * 16 + e);
            h[e] = (bin <= 3072u) ? s_hist[skew(bin)] : 0u;  // clamp (r7)
            hsum += h[e];
        }
        unsigned v = hsum;
        #pragma unroll
        for (int off = 1; off < 64; off <<= 1) {
            const unsigned o = __shfl_down(v, off, 64);
            if (lane + off < 64) v += o;
        }
        if (lane == 0) s_wtot[wid] = v;
        __syncthreads();
        unsigned G = v;
        for (int w = wid + 1; w < 4; ++w) G += s_wtot[w];
        s_G[t] = G;
        __syncthreads();
        const unsigned Gn = (t < NT - 1) ? s_G[t + 1] : 0u;

        if (G >= (unsigned)NK && Gn < (unsigned)NK) {
            unsigned above = Gn;
            #pragma unroll
            for (int e = 15; e >= 0; --e) {
                if (above + h[e] >= (unsigned)NK) {
                    s_digit = (unsigned)(t * 16 + e);
                    break;
                }
                above += h[e];
            }
        }
        __syncthreads();

        // conservative float edge of bin D (each op exact; slack 2^-18)
        const unsigned D = s_digit;
        const float edge = ((float)D * 0.0078125f - 24.0f) - 0x1p-18f;

        // survivor pass: pd >= edge -> (index, exact sign-flipped key)
        #pragma unroll
        for (int m = 0; m < PERT; ++m) {
            if (pdv[q][m] >= edge) {
                const unsigned p = atomicAdd(&s_scnt, 1u);
                if (p < 256u) {
                    const unsigned u = __float_as_uint(pdv[q][m]);
                    s_sj[p] = m * NT + t;
                    s_sk[p] = (u & 0x80000000u) ? ~u : (u | 0x80000000u);
                }
            }
        }
        __syncthreads();

        const int sc = (int)min(s_scnt, 256u);

        // exact top-32 among survivors by (key desc, idx asc)
        if (wid == 0) {
            if (sc <= 64) {
                unsigned long long comp = 0ull;
                if (lane < sc)
                    comp = ((unsigned long long)s_sk[lane] << 32) |
                           (unsigned)(~(unsigned)s_sj[lane]);
                #pragma unroll
                for (int k = 2; k <= 64; k <<= 1) {
                    #pragma unroll
                    for (int jj = k >> 1; jj >= 1; jj >>= 1) {
                        const unsigned long long other = __shfl_xor(comp, jj, 64);
                        const bool dirDesc = ((lane & k) == 0);
                        const bool isLow   = ((lane & jj) == 0);
                        const bool wantMax = (dirDesc == isLow);
                        const bool otherBigger = other > comp;
                        comp = (wantMax == otherBigger) ? other : comp;
                    }
                }
                if (lane < NK)
                    s_sel[lane] = (int)(~(unsigned)(comp & 0xffffffffull));
            } else {
                // rare path (65..256 survivors): 4/lane, 32 extraction rounds
                unsigned long long c[4];
                #pragma unroll
                for (int p4 = 0; p4 < 4; ++p4) {
                    const int idx = lane + 64 * p4;
                    c[p4] = (idx < sc)
                          ? (((unsigned long long)s_sk[idx] << 32) |
                             (unsigned)(~(unsigned)s_sj[idx]))
                          : 0ull;
                }
                for (int r = 0; r < NK; ++r) {
                    unsigned long long w = c[0];
                    #pragma unroll
                    for (int p4 = 1; p4 < 4; ++p4) if (c[p4] > w) w = c[p4];
                    #pragma unroll
                    for (int off = 32; off >= 1; off >>= 1) {
                        const unsigned long long o = __shfl_xor(w, off, 64);
                        if (o > w) w = o;
                    }
                    #pragma unroll
                    for (int p4 = 0; p4 < 4; ++p4) if (c[p4] == w) c[p4] = 0ull;
                    if (lane == 0)
                        s_sel[r] = (int)(~(unsigned)(w & 0xffffffffull));
                }
            }
        }
        __syncthreads();

        // ---- mean-pool the 32 selected rows ----
        const int c    = t & (NC - 1);
        const int half = t >> 7;
        float sum = 0.f;
        #pragma unroll
        for (int k = 0; k < NK / 2; ++k) {
            const int j = s_sel[half * (NK / 2) + k] & (NP - 1); // fault-proof
            sum += fb[(size_t)j * NC + c];
        }
        s_red[t] = sum;
        __syncthreads();
        if (t < NC) {
            const float p = (s_red[t] + s_red[t + NC]) * (1.0f / (float)NK);
            pooled[(size_t)((b << 12) | (i0 + q)) * NC + t] = p;
        }
        __syncthreads();   // protect s_red/s_sel before next query's zeroing
    }
}

// ---------------------------------------------------------------------------
// Kernel B: in-place Linear on d_out rows: io[row,d] = sum_c io[row,c]*W[d,c]
// ---------------------------------------------------------------------------
__global__ __launch_bounds__(NT) void linear_kernel(
    float* __restrict__ io,           // [B*N, C] fp32, in-place
    const float* __restrict__ W)      // [C, C] row-major W[d][c]
{
    const int t    = threadIdx.x;
    const int row0 = blockIdx.x * 64;

    __shared__ float P[64 * NC];  // 32 KiB

    const float* src = io + (size_t)row0 * NC;
    #pragma unroll
    for (int m = 0; m < 8; ++m) {
        const int e4 = m * NT + t;
        *(float4*)&P[e4 * 4] = *(const float4*)&src[e4 * 4];
    }
    __syncthreads();

    const int d     = t & (NC - 1);
    const int rbase = (t >> 7) * 32;

    float acc[32];
    #pragma unroll
    for (int k = 0; k < 32; ++k) acc[k] = 0.f;

    const float* Wd = W + (size_t)d * NC;
    for (int c4 = 0; c4 < NC / 4; ++c4) {
        const float4 w = *(const float4*)(Wd + c4 * 4);
        #pragma unroll
        for (int k = 0; k < 32; ++k) {
            const float4 pv = *(const float4*)&P[(rbase + k) * NC + c4 * 4];
            acc[k] = fmaf(pv.x, w.x, acc[k]);
            acc[k] = fmaf(pv.y, w.y, acc[k]);
            acc[k] = fmaf(pv.z, w.z, acc[k]);
            acc[k] = fmaf(pv.w, w.w, acc[k]);
        }
    }

    #pragma unroll
    for (int k = 0; k < 32; ++k) {
        io[(size_t)(row0 + rbase + k) * NC + d] = acc[k];
    }
}

// ---------------------------------------------------------------------------
extern "C" void kernel_launch(void* const* d_in, const int* in_sizes, int n_in,
                              void* d_out, int out_size, void* d_ws, size_t ws_size,
                              hipStream_t stream) {
    const float* xyz   = nullptr;  // 49152
    const float* feats = nullptr;  // 2097152
    const float* W     = nullptr;  // 16384
    for (int k = 0; k < n_in; ++k) {
        if      (in_sizes[k] == NB * 3 * NP)       xyz   = (const float*)d_in[k];
        else if (in_sizes[k] == NB * NP * NC)      feats = (const float*)d_in[k];
        else if (in_sizes[k] == NC * NC)           W     = (const float*)d_in[k];
    }
    float* out = (float*)d_out;

    if (ws_size >= sizeof(float) * (size_t)(NB * NP)) {
        float* xxw = (float*)d_ws;
        precompute_kernel<<<NB * NP / NT, NT, 0, stream>>>(xyz, xxw);
        knn_pool_kernel<true><<<NB * NP / NQ, NT, 0, stream>>>(xyz, xxw, feats, out);
    } else {
        knn_pool_kernel<false><<<NB * NP / NQ, NT, 0, stream>>>(xyz, nullptr, feats, out);
    }
    linear_kernel<<<NB * NP / 64, NT, 0, stream>>>(out, W);
}

// Round 13
// 125.025 us; speedup vs baseline: 1.0727x; 1.0727x over previous
//
#include <hip/hip_runtime.h>
#include <hip/hip_bf16.h>

// Forbid FMA contraction for plain fp expressions in ALL device code below:
// the kNN ranking must bit-match the reference's uncontracted fp32 expression
//   pd[i,j] = 2*inner(i,j) - xx[i] - xx[j]
// (rounds 4/6/8/10/11 passed uncontracted; round 5 regressed when the
// compiler fused 2*inner-xxi into v_fma_f32). Explicit fmaf() calls are NOT
// affected by this pragma -- the approx prefilter exploits exactly that.
#pragma clang fp contract(off)

// B=4, N=4096, C=128, K=32. All fp32. top-K LARGEST pd, tie -> lowest index.
// Round 13 (r11 skeleton, 44-VGPR band):
//   - main loop computes APPROX pd via fmaf (6 fp vs 11), tracks thread max
//   - threshold = r11 conservative bin edge MINUS 2^-11 margin: covers the
//     <=1e-4 approx-vs-exact rounding gap, so all exact-top-32 survive
//   - survivors (~38) get their EXACT uncontracted pd recomputed one thread
//     each (L1-hot reloads); bitonic ranks exact keys => bits match r11
//   - pool vectorized: 4 rows x 4 channels per thread, float4 loads
// r12 lesson: keep VGPR < 48 (Q=4 blew occupancy 50%->40%, lost its gain).

constexpr int NB   = 4;
constexpr int NP   = 4096;
constexpr int NC   = 128;
constexpr int NK   = 32;
constexpr int NT   = 256;
constexpr int PERT = NP / NT; // 16

__device__ __forceinline__ unsigned skew(unsigned d) { return d + (d >> 5); }

// ---------------------------------------------------------------------------
// Kernel P: xxw[b*NP+j] = xx_j, bit-identical to the reference's
// uncontracted (x*x + y*y) + z*z.
// ---------------------------------------------------------------------------
__global__ __launch_bounds__(NT) void precompute_kernel(
    const float* __restrict__ xyz,    // [B,3,N]
    float* __restrict__ xxw)          // [B*NP]
{
    const int g = blockIdx.x * NT + threadIdx.x;   // 0 .. B*NP-1
    const int b = g >> 12;
    const int j = g & (NP - 1);
    const float* xb = xyz + (size_t)b * 3 * NP;
    const float x = xb[j];
    const float y = xb[NP + j];
    const float z = xb[2 * NP + j];
    xxw[g] = (x * x + y * y) + z * z;              // each op rounded (no FMA)
}

// ---------------------------------------------------------------------------
// Kernel A: per-query kNN (approx prefilter + exact refine) + mean pool.
// ---------------------------------------------------------------------------
template <bool USE_WS>
__global__ __launch_bounds__(NT) void knn_pool_kernel(
    const float* __restrict__ xyz,    // [B,3,N]
    const float* __restrict__ xxw,    // [B*NP] (USE_WS only)
    const float* __restrict__ feats,  // [B,N,C]
    float* __restrict__ pooled)       // [B*N, C] (d_out, fp32 temp)
{
    const int bi   = blockIdx.x;
    const int b    = bi >> 12;
    const int i    = bi & (NP - 1);
    const int t    = threadIdx.x;
    const int lane = t & 63;
    const int wid  = t >> 6;

    const float* xb  = xyz + (size_t)b * 3 * NP;
    const float* xxb = USE_WS ? (xxw + ((size_t)b << 12)) : nullptr;

    const float qx = xb[i];
    const float qy = xb[NP + i];
    const float qz = xb[2 * NP + i];
    float xxi;
    if constexpr (USE_WS) xxi = xxb[i];
    else                  xxi = (qx * qx + qy * qy) + qz * qz;

    // APPROX pd (fmaf, 6 fp/candidate) + running thread-max.
    // |pd_a - pd_exact| <= ~1e-4 (13 roundings at ulp<=2^-16); margin below.
    float pda[PERT];
    float tmax = -3.0e38f;
    #pragma unroll
    for (int m = 0; m < PERT; ++m) {
        const int j = m * NT + t;
        const float px = xb[j];
        const float py = xb[NP + j];
        const float pz = xb[2 * NP + j];
        float xxj;
        if constexpr (USE_WS) xxj = xxb[j];     // 4B scalar, L1-resident
        else                  xxj = (px * px + py * py) + pz * pz;
        const float inner_a = fmaf(qx, px, fmaf(qy, py, qz * pz));
        const float pd_a    = fmaf(2.0f, inner_a, -xxi) - xxj;
        pda[m] = pd_a;
        tmax = fmaxf(tmax, pd_a);
    }
    // bin of the thread max (monotone uniformized map, as r11)
    const float qm = fmaxf(tmax + 24.0f, 0.0f) * 67108864.0f;  // *2^26, exact
    const unsigned dgmax = min(((unsigned)qm) >> 19, 3072u);    // 0..3072

    __shared__ unsigned s_hist[3200];   // 3073 skewed bins (12.8 KiB)
    __shared__ int      s_sel[NK];
    __shared__ int      s_sj[256];
    __shared__ unsigned s_sk[256];
    __shared__ unsigned s_G[NT];
    __shared__ unsigned s_wtot[4];
    __shared__ unsigned s_scnt, s_digit;
    __shared__ float4   s_red4[NT];     // 4 KiB pool reduction

    if (t == 0) { s_scnt = 0; s_digit = 0; }
    if (t < NK) s_sel[t] = 0;           // defensive: never leave garbage
    {   // wide zeroing: 800 uint4 across 256 threads
        uint4* hz = (uint4*)s_hist;
        for (int z = t; z < 800; z += NT) hz[z] = make_uint4(0u, 0u, 0u, 0u);
    }
    __syncthreads();

    // -- histogram of the 256 thread-maxima (1 atomic per thread) --
    atomicAdd(&s_hist[skew(dgmax)], 1u);
    __syncthreads();

    // -- block suffix scan (verbatim r11): G[t] = # maxima with bin >= 16*t --
    unsigned h[16];
    unsigned hsum = 0;
    #pragma unroll
    for (int e = 0; e < 16; ++e) {
        const unsigned bin = (unsigned)(t * 16 + e);
        h[e] = (bin <= 3072u) ? s_hist[skew(bin)] : 0u;   // clamp (r7 lesson)
        hsum += h[e];
    }
    unsigned v = hsum;
    #pragma unroll
    for (int off = 1; off < 64; off <<= 1) {
        const unsigned o = __shfl_down(v, off, 64);
        if (lane + off < 64) v += o;
    }
    if (lane == 0) s_wtot[wid] = v;
    __syncthreads();
    unsigned G = v;
    for (int w = wid + 1; w < 4; ++w) G += s_wtot[w];
    s_G[t] = G;
    __syncthreads();
    const unsigned Gn = (t < NT - 1) ? s_G[t + 1] : 0u;

    if (G >= (unsigned)NK && Gn < (unsigned)NK) {
        unsigned above = Gn;
        #pragma unroll
        for (int e = 15; e >= 0; --e) {
            if (above + h[e] >= (unsigned)NK) {
                s_digit = (unsigned)(t * 16 + e);
                break;
            }
            above += h[e];
        }
    }
    __syncthreads();

    // Conservative edge (r11) minus approx-vs-exact margin 2^-11 (~4.9e-4,
    // >=4x the bounded 1e-4 discrepancy): every exact-top-32 survives.
    const unsigned D = s_digit;
    const float thr = (((float)D * 0.0078125f - 24.0f) - 0x1p-18f) - 0x1p-11f;

    // -- survivor pass: push index only --
    #pragma unroll
    for (int m = 0; m < PERT; ++m) {
        if (pda[m] >= thr) {
            const unsigned p = atomicAdd(&s_scnt, 1u);
            if (p < 256u) s_sj[p] = m * NT + t;
        }
    }
    __syncthreads();

    const int sc = (int)min(s_scnt, 256u);

    // -- exact re-key: one thread per survivor, uncontracted reference bits --
    if (t < sc) {
        const int j = s_sj[t];
        const float px = xb[j];
        const float py = xb[NP + j];
        const float pz = xb[2 * NP + j];
        float xxj;
        if constexpr (USE_WS) xxj = xxb[j];
        else                  xxj = (px * px + py * py) + pz * pz;
        const float inner = (qx * px + qy * py) + qz * pz;   // no FMA (pragma)
        const float pd    = (2.0f * inner - xxi) - xxj;      // no FMA (pragma)
        const unsigned u  = __float_as_uint(pd);
        s_sk[t] = (u & 0x80000000u) ? ~u : (u | 0x80000000u);
    }
    __syncthreads();

    // -- exact top-32 among survivors by (key desc, idx asc) --
    if (wid == 0) {
        if (sc <= 64) {
            unsigned long long comp = 0ull;   // padding sorts below all real
            if (lane < sc)
                comp = ((unsigned long long)s_sk[lane] << 32) |
                       (unsigned)(~(unsigned)s_sj[lane]);
            #pragma unroll
            for (int k = 2; k <= 64; k <<= 1) {
                #pragma unroll
                for (int jj = k >> 1; jj >= 1; jj >>= 1) {
                    const unsigned long long other = __shfl_xor(comp, jj, 64);
                    const bool dirDesc = ((lane & k) == 0);
                    const bool isLow   = ((lane & jj) == 0);
                    const bool wantMax = (dirDesc == isLow);
                    const bool otherBigger = other > comp;
                    comp = (wantMax == otherBigger) ? other : comp;
                }
            }
            if (lane < NK)
                s_sel[lane] = (int)(~(unsigned)(comp & 0xffffffffull));
        } else {
            // rare path (65..256 survivors): 4/lane, 32 extraction rounds
            unsigned long long c[4];
            #pragma unroll
            for (int q = 0; q < 4; ++q) {
                const int idx = lane + 64 * q;
                c[q] = (idx < sc)
                     ? (((unsigned long long)s_sk[idx] << 32) |
                        (unsigned)(~(unsigned)s_sj[idx]))
                     : 0ull;
            }
            for (int r = 0; r < NK; ++r) {
                unsigned long long w = c[0];
                #pragma unroll
                for (int q = 1; q < 4; ++q) if (c[q] > w) w = c[q];
                #pragma unroll
                for (int off = 32; off >= 1; off >>= 1) {
                    const unsigned long long o = __shfl_xor(w, off, 64);
                    if (o > w) w = o;
                }
                #pragma unroll
                for (int q = 0; q < 4; ++q) if (c[q] == w) c[q] = 0ull;
                if (lane == 0)
                    s_sel[r] = (int)(~(unsigned)(w & 0xffffffffull));
            }
        }
    }
    __syncthreads();

    // -- mean-pool, vectorized: thread = (row-group rg, channel-group cg) --
    const int cg = t & 31;    // channels 4*cg .. 4*cg+3
    const int rg = t >> 5;    // rows 4*rg .. 4*rg+3  (8 groups x 4 rows = 32)
    const float* fb = feats + (size_t)b * NP * NC;
    float ax = 0.f, ay = 0.f, az = 0.f, aw = 0.f;
    #pragma unroll
    for (int k = 0; k < 4; ++k) {
        const int j = s_sel[rg * 4 + k] & (NP - 1);   // fault-proof mask
        const float4 f = *(const float4*)&fb[(size_t)j * NC + cg * 4];
        ax += f.x; ay += f.y; az += f.z; aw += f.w;
    }
    s_red4[t] = make_float4(ax, ay, az, aw);
    __syncthreads();
    if (t < 32) {
        float4 s = s_red4[t];
        #pragma unroll
        for (int g2 = 1; g2 < 8; ++g2) {
            const float4 o = s_red4[g2 * 32 + t];
            s.x += o.x; s.y += o.y; s.z += o.z; s.w += o.w;
        }
        const float inv = 1.0f / (float)NK;
        s.x *= inv; s.y *= inv; s.z *= inv; s.w *= inv;
        *(float4*)&pooled[(size_t)bi * NC + t * 4] = s;
    }
}

// ---------------------------------------------------------------------------
// Kernel B: in-place Linear on d_out rows: io[row,d] = sum_c io[row,c]*W[d,c]
// ---------------------------------------------------------------------------
__global__ __launch_bounds__(NT) void linear_kernel(
    float* __restrict__ io,           // [B*N, C] fp32, in-place
    const float* __restrict__ W)      // [C, C] row-major W[d][c]
{
    const int t    = threadIdx.x;
    const int row0 = blockIdx.x * 64;

    __shared__ float P[64 * NC];  // 32 KiB

    const float* src = io + (size_t)row0 * NC;
    #pragma unroll
    for (int m = 0; m < 8; ++m) {
        const int e4 = m * NT + t;
        *(float4*)&P[e4 * 4] = *(const float4*)&src[e4 * 4];
    }
    __syncthreads();

    const int d     = t & (NC - 1);
    const int rbase = (t >> 7) * 32;

    float acc[32];
    #pragma unroll
    for (int k = 0; k < 32; ++k) acc[k] = 0.f;

    const float* Wd = W + (size_t)d * NC;
    for (int c4 = 0; c4 < NC / 4; ++c4) {
        const float4 w = *(const float4*)(Wd + c4 * 4);
        #pragma unroll
        for (int k = 0; k < 32; ++k) {
            const float4 pv = *(const float4*)&P[(rbase + k) * NC + c4 * 4];
            acc[k] = fmaf(pv.x, w.x, acc[k]);
            acc[k] = fmaf(pv.y, w.y, acc[k]);
            acc[k] = fmaf(pv.z, w.z, acc[k]);
            acc[k] = fmaf(pv.w, w.w, acc[k]);
        }
    }

    #pragma unroll
    for (int k = 0; k < 32; ++k) {
        io[(size_t)(row0 + rbase + k) * NC + d] = acc[k];
    }
}

// ---------------------------------------------------------------------------
extern "C" void kernel_launch(void* const* d_in, const int* in_sizes, int n_in,
                              void* d_out, int out_size, void* d_ws, size_t ws_size,
                              hipStream_t stream) {
    const float* xyz   = nullptr;  // 49152
    const float* feats = nullptr;  // 2097152
    const float* W     = nullptr;  // 16384
    for (int k = 0; k < n_in; ++k) {
        if      (in_sizes[k] == NB * 3 * NP)       xyz   = (const float*)d_in[k];
        else if (in_sizes[k] == NB * NP * NC)      feats = (const float*)d_in[k];
        else if (in_sizes[k] == NC * NC)           W     = (const float*)d_in[k];
    }
    float* out = (float*)d_out;

    if (ws_size >= sizeof(float) * (size_t)(NB * NP)) {
        float* xxw = (float*)d_ws;
        precompute_kernel<<<NB * NP / NT, NT, 0, stream>>>(xyz, xxw);
        knn_pool_kernel<true><<<NB * NP, NT, 0, stream>>>(xyz, xxw, feats, out);
    } else {
        knn_pool_kernel<false><<<NB * NP, NT, 0, stream>>>(xyz, nullptr, feats, out);
    }
    linear_kernel<<<NB * NP / 64, NT, 0, stream>>>(out, W);
}

// Round 14
// 118.086 us; speedup vs baseline: 1.1358x; 1.0588x over previous
//
#include <hip/hip_runtime.h>
#include <hip/hip_bf16.h>

// Forbid FMA contraction for plain fp expressions in ALL device code below:
// the kNN ranking must bit-match the reference's uncontracted fp32 expression
//   pd[i,j] = 2*inner(i,j) - xx[i] - xx[j]
// (rounds 4/6/8/10/11/13 passed uncontracted; round 5 regressed when the
// compiler fused 2*inner-xxi into v_fma_f32). Explicit fmaf() calls are NOT
// affected by this pragma -- the approx prefilter exploits exactly that.
#pragma clang fp contract(off)

// B=4, N=4096, C=128, K=32. All fp32. top-K LARGEST pd, tie -> lowest index.
// Round 14:
//   - NEW linear: W transposed once into ws (Wt[c][d]); 1024 blocks x 16 rows,
//     coalesced/broadcast reads, full per-thread inner sums. Old linear ran at
//     1 block/CU with 64-line-scattered W reads -- suspected ~20-25us hidden
//     cost (the persistent dur_us-vs-dispatch-sum gap).
//   - knn micro: s_G array + 1 barrier removed (Gn via shfl_down + tail
//     identity); histogram halved to 1537 bins (>>20), margin re-derived.
//   - Selection core (approx-fmaf prefilter, conservative edge, exact re-key,
//     bitonic refinement) is r13-verbatim.

constexpr int NB   = 4;
constexpr int NP   = 4096;
constexpr int NC   = 128;
constexpr int NK   = 32;
constexpr int NT   = 256;
constexpr int PERT = NP / NT; // 16

__device__ __forceinline__ unsigned skew(unsigned d) { return d + (d >> 5); }

// ---------------------------------------------------------------------------
// Kernel P: blocks 0..63: xxw[b*NP+j] = (x*x + y*y) + z*z (uncontracted,
// bit-identical to reference xx). Block 64: Wt[c][d] = W[d][c].
// ---------------------------------------------------------------------------
__global__ __launch_bounds__(NT) void precompute_kernel(
    const float* __restrict__ xyz,    // [B,3,N]
    const float* __restrict__ W,      // [C,C]
    float* __restrict__ xxw,          // [B*NP]
    float* __restrict__ Wt)           // [C,C] transposed
{
    const int blk = blockIdx.x;
    const int t   = threadIdx.x;
    if (blk < 64) {
        const int g = blk * NT + t;                // 0 .. B*NP-1
        const int b = g >> 12;
        const int j = g & (NP - 1);
        const float* xb = xyz + (size_t)b * 3 * NP;
        const float x = xb[j];
        const float y = xb[NP + j];
        const float z = xb[2 * NP + j];
        xxw[g] = (x * x + y * y) + z * z;          // each op rounded (no FMA)
    } else {
        for (int e = t; e < NC * NC; e += NT) {
            const int d = e >> 7;
            const int c = e & (NC - 1);
            Wt[c * NC + d] = W[e];                 // coalesced read
        }
    }
}

// ---------------------------------------------------------------------------
// Kernel A: per-query kNN (approx prefilter + exact refine) + mean pool.
// ---------------------------------------------------------------------------
template <bool USE_WS>
__global__ __launch_bounds__(NT) void knn_pool_kernel(
    const float* __restrict__ xyz,    // [B,3,N]
    const float* __restrict__ xxw,    // [B*NP] (USE_WS only)
    const float* __restrict__ feats,  // [B,N,C]
    float* __restrict__ pooled)       // [B*N, C] (d_out, fp32 temp)
{
    const int bi   = blockIdx.x;
    const int b    = bi >> 12;
    const int i    = bi & (NP - 1);
    const int t    = threadIdx.x;
    const int lane = t & 63;
    const int wid  = t >> 6;

    const float* xb  = xyz + (size_t)b * 3 * NP;
    const float* xxb = USE_WS ? (xxw + ((size_t)b << 12)) : nullptr;

    const float qx = xb[i];
    const float qy = xb[NP + i];
    const float qz = xb[2 * NP + i];
    float xxi;
    if constexpr (USE_WS) xxi = xxb[i];
    else                  xxi = (qx * qx + qy * qy) + qz * qz;

    // APPROX pd (fmaf) + running thread-max. |pd_a - pd_exact| <= ~1e-4.
    float pda[PERT];
    float tmax = -3.0e38f;
    #pragma unroll
    for (int m = 0; m < PERT; ++m) {
        const int j = m * NT + t;
        const float px = xb[j];
        const float py = xb[NP + j];
        const float pz = xb[2 * NP + j];
        float xxj;
        if constexpr (USE_WS) xxj = xxb[j];     // 4B scalar, L1-resident
        else                  xxj = (px * px + py * py) + pz * pz;
        const float inner_a = fmaf(qx, px, fmaf(qy, py, qz * pz));
        const float pd_a    = fmaf(2.0f, inner_a, -xxi) - xxj;
        pda[m] = pd_a;
        tmax = fmaxf(tmax, pd_a);
    }
    // bin of thread max: trunc(max(pd+24,0)*2^26) >> 20, 0..1536 (width 2^-6)
    const float qm = fmaxf(tmax + 24.0f, 0.0f) * 67108864.0f;  // *2^26, exact
    const unsigned dgmax = min(((unsigned)qm) >> 20, 1536u);

    __shared__ unsigned s_hist[1600];   // 1537 skewed bins (6.4 KiB)
    __shared__ int      s_sel[NK];
    __shared__ int      s_sj[256];
    __shared__ unsigned s_sk[256];
    __shared__ unsigned s_wtot[4];
    __shared__ unsigned s_scnt, s_digit;
    __shared__ float4   s_red4[NT];     // 4 KiB pool reduction

    if (t == 0) { s_scnt = 0; s_digit = 0; }
    if (t < NK) s_sel[t] = 0;           // defensive: never leave garbage
    {   // wide zeroing: 400 uint4 across 256 threads
        uint4* hz = (uint4*)s_hist;
        for (int z = t; z < 400; z += NT) hz[z] = make_uint4(0u, 0u, 0u, 0u);
    }
    __syncthreads();

    // -- histogram of the 256 thread-maxima (1 atomic per thread) --
    atomicAdd(&s_hist[skew(dgmax)], 1u);
    __syncthreads();

    // -- block suffix scan, no s_G array: G via wave shfl + cross-wave tail --
    unsigned h[8];
    unsigned hsum = 0;
    #pragma unroll
    for (int e = 0; e < 8; ++e) {
        const unsigned bin = (unsigned)(t * 8 + e);
        h[e] = (bin <= 1536u) ? s_hist[skew(bin)] : 0u;   // clamp (r7 lesson)
        hsum += h[e];
    }
    unsigned v = hsum;   // becomes within-wave suffix sum (incl. self)
    #pragma unroll
    for (int off = 1; off < 64; off <<= 1) {
        const unsigned o = __shfl_down(v, off, 64);
        if (lane + off < 64) v += o;
    }
    if (lane == 0) s_wtot[wid] = v;
    __syncthreads();
    unsigned tail = 0;
    for (int w = wid + 1; w < 4; ++w) tail += s_wtot[w];
    const unsigned G  = v + tail;
    const unsigned nb = __shfl_down(G, 1, 64);
    // identity: next wave's G[0] == this wave's tail (so lane 63 uses tail)
    const unsigned Gn = (lane == 63) ? tail : nb;

    if (G >= (unsigned)NK && Gn < (unsigned)NK) {
        unsigned above = Gn;
        #pragma unroll
        for (int e = 7; e >= 0; --e) {
            if (above + h[e] >= (unsigned)NK) {
                s_digit = (unsigned)(t * 8 + e);
                break;
            }
            above += h[e];
        }
    }
    __syncthreads();

    // Conservative edge of bin D (width 2^-6; exact steps) minus approx
    // margin 2^-11 (>=4x the bounded ~1e-4 fmaf-vs-uncontracted gap).
    const unsigned D = s_digit;
    const float thr = (((float)D * 0.015625f - 24.0f) - 0x1p-18f) - 0x1p-11f;

    // -- survivor pass: push index only --
    #pragma unroll
    for (int m = 0; m < PERT; ++m) {
        if (pda[m] >= thr) {
            const unsigned p = atomicAdd(&s_scnt, 1u);
            if (p < 256u) s_sj[p] = m * NT + t;
        }
    }
    __syncthreads();

    const int sc = (int)min(s_scnt, 256u);

    // -- exact re-key: one thread per survivor, uncontracted reference bits --
    if (t < sc) {
        const int j = s_sj[t];
        const float px = xb[j];
        const float py = xb[NP + j];
        const float pz = xb[2 * NP + j];
        float xxj;
        if constexpr (USE_WS) xxj = xxb[j];
        else                  xxj = (px * px + py * py) + pz * pz;
        const float inner = (qx * px + qy * py) + qz * pz;   // no FMA (pragma)
        const float pd    = (2.0f * inner - xxi) - xxj;      // no FMA (pragma)
        const unsigned u  = __float_as_uint(pd);
        s_sk[t] = (u & 0x80000000u) ? ~u : (u | 0x80000000u);
    }
    __syncthreads();

    // -- exact top-32 among survivors by (key desc, idx asc) --
    if (wid == 0) {
        if (sc <= 64) {
            unsigned long long comp = 0ull;   // padding sorts below all real
            if (lane < sc)
                comp = ((unsigned long long)s_sk[lane] << 32) |
                       (unsigned)(~(unsigned)s_sj[lane]);
            #pragma unroll
            for (int k = 2; k <= 64; k <<= 1) {
                #pragma unroll
                for (int jj = k >> 1; jj >= 1; jj >>= 1) {
                    const unsigned long long other = __shfl_xor(comp, jj, 64);
                    const bool dirDesc = ((lane & k) == 0);
                    const bool isLow   = ((lane & jj) == 0);
                    const bool wantMax = (dirDesc == isLow);
                    const bool otherBigger = other > comp;
                    comp = (wantMax == otherBigger) ? other : comp;
                }
            }
            if (lane < NK)
                s_sel[lane] = (int)(~(unsigned)(comp & 0xffffffffull));
        } else {
            // rare path (65..256 survivors): 4/lane, 32 extraction rounds
            unsigned long long c[4];
            #pragma unroll
            for (int q = 0; q < 4; ++q) {
                const int idx = lane + 64 * q;
                c[q] = (idx < sc)
                     ? (((unsigned long long)s_sk[idx] << 32) |
                        (unsigned)(~(unsigned)s_sj[idx]))
                     : 0ull;
            }
            for (int r = 0; r < NK; ++r) {
                unsigned long long w = c[0];
                #pragma unroll
                for (int q = 1; q < 4; ++q) if (c[q] > w) w = c[q];
                #pragma unroll
                for (int off = 32; off >= 1; off >>= 1) {
                    const unsigned long long o = __shfl_xor(w, off, 64);
                    if (o > w) w = o;
                }
                #pragma unroll
                for (int q = 0; q < 4; ++q) if (c[q] == w) c[q] = 0ull;
                if (lane == 0)
                    s_sel[r] = (int)(~(unsigned)(w & 0xffffffffull));
            }
        }
    }
    __syncthreads();

    // -- mean-pool, vectorized: thread = (row-group rg, channel-group cg) --
    const int cg = t & 31;    // channels 4*cg .. 4*cg+3
    const int rg = t >> 5;    // rows 4*rg .. 4*rg+3
    const float* fb = feats + (size_t)b * NP * NC;
    float ax = 0.f, ay = 0.f, az = 0.f, aw = 0.f;
    #pragma unroll
    for (int k = 0; k < 4; ++k) {
        const int j = s_sel[rg * 4 + k] & (NP - 1);   // fault-proof mask
        const float4 f = *(const float4*)&fb[(size_t)j * NC + cg * 4];
        ax += f.x; ay += f.y; az += f.z; aw += f.w;
    }
    s_red4[t] = make_float4(ax, ay, az, aw);
    __syncthreads();
    if (t < 32) {
        float4 s = s_red4[t];
        #pragma unroll
        for (int g2 = 1; g2 < 8; ++g2) {
            const float4 o = s_red4[g2 * 32 + t];
            s.x += o.x; s.y += o.y; s.z += o.z; s.w += o.w;
        }
        const float inv = 1.0f / (float)NK;
        s.x *= inv; s.y *= inv; s.z *= inv; s.w *= inv;
        *(float4*)&pooled[(size_t)bi * NC + t * 4] = s;
    }
}

// ---------------------------------------------------------------------------
// Kernel B (new): in-place Linear with transposed W. 1024 blocks x 16 rows.
// out[row,d] = sum_c P[row,c] * Wt[c,d]; coalesced Wt reads (lanes span d),
// LDS broadcast P reads, full inner sums in registers, coalesced writes.
// Same c-ascending fmaf order as the previous linear kernel.
// ---------------------------------------------------------------------------
constexpr int LROWS = 16;
__global__ __launch_bounds__(NT) void linear_t_kernel(
    float* __restrict__ io,           // [B*N, C] fp32, in-place
    const float* __restrict__ Wt)     // [C, C] transposed: Wt[c][d]
{
    const int t    = threadIdx.x;
    const int row0 = blockIdx.x * LROWS;

    __shared__ float P[LROWS * NC];   // 8 KiB

    const float4* src4 = (const float4*)(io + (size_t)row0 * NC);
    ((float4*)P)[t]       = src4[t];
    ((float4*)P)[t + NT]  = src4[t + NT];
    __syncthreads();

    const int dg = t & 31;            // d = 4*dg .. 4*dg+3
    const int rg = t >> 5;            // rows 2*rg, 2*rg+1
    const int r0 = rg * 2, r1 = r0 + 1;

    float4 a0 = make_float4(0.f, 0.f, 0.f, 0.f);
    float4 a1 = make_float4(0.f, 0.f, 0.f, 0.f);
    const float4* Wt4 = (const float4*)Wt;   // row c = 32 float4

    #pragma unroll 4
    for (int c = 0; c < NC; ++c) {
        const float4 w = Wt4[c * 32 + dg];   // coalesced across 32 lanes
        const float p0 = P[r0 * NC + c];     // broadcast within lane group
        const float p1 = P[r1 * NC + c];
        a0.x = fmaf(p0, w.x, a0.x); a0.y = fmaf(p0, w.y, a0.y);
        a0.z = fmaf(p0, w.z, a0.z); a0.w = fmaf(p0, w.w, a0.w);
        a1.x = fmaf(p1, w.x, a1.x); a1.y = fmaf(p1, w.y, a1.y);
        a1.z = fmaf(p1, w.z, a1.z); a1.w = fmaf(p1, w.w, a1.w);
    }

    float4* dst4 = (float4*)(io + (size_t)row0 * NC);
    dst4[r0 * 32 + dg] = a0;          // all staging reads done pre-barrier
    dst4[r1 * 32 + dg] = a1;
}

// ---------------------------------------------------------------------------
// Kernel B (fallback, ws-less): previous 64-row in-place linear.
// ---------------------------------------------------------------------------
__global__ __launch_bounds__(NT) void linear_kernel(
    float* __restrict__ io, const float* __restrict__ W)
{
    const int t    = threadIdx.x;
    const int row0 = blockIdx.x * 64;
    __shared__ float P[64 * NC];
    const float* src = io + (size_t)row0 * NC;
    #pragma unroll
    for (int m = 0; m < 8; ++m) {
        const int e4 = m * NT + t;
        *(float4*)&P[e4 * 4] = *(const float4*)&src[e4 * 4];
    }
    __syncthreads();
    const int d = t & (NC - 1);
    const int rbase = (t >> 7) * 32;
    float acc[32];
    #pragma unroll
    for (int k = 0; k < 32; ++k) acc[k] = 0.f;
    const float* Wd = W + (size_t)d * NC;
    for (int c4 = 0; c4 < NC / 4; ++c4) {
        const float4 w = *(const float4*)(Wd + c4 * 4);
        #pragma unroll
        for (int k = 0; k < 32; ++k) {
            const float4 pv = *(const float4*)&P[(rbase + k) * NC + c4 * 4];
            acc[k] = fmaf(pv.x, w.x, acc[k]);
            acc[k] = fmaf(pv.y, w.y, acc[k]);
            acc[k] = fmaf(pv.z, w.z, acc[k]);
            acc[k] = fmaf(pv.w, w.w, acc[k]);
        }
    }
    #pragma unroll
    for (int k = 0; k < 32; ++k)
        io[(size_t)(row0 + rbase + k) * NC + d] = acc[k];
}

// ---------------------------------------------------------------------------
extern "C" void kernel_launch(void* const* d_in, const int* in_sizes, int n_in,
                              void* d_out, int out_size, void* d_ws, size_t ws_size,
                              hipStream_t stream) {
    const float* xyz   = nullptr;  // 49152
    const float* feats = nullptr;  // 2097152
    const float* W     = nullptr;  // 16384
    for (int k = 0; k < n_in; ++k) {
        if      (in_sizes[k] == NB * 3 * NP)       xyz   = (const float*)d_in[k];
        else if (in_sizes[k] == NB * NP * NC)      feats = (const float*)d_in[k];
        else if (in_sizes[k] == NC * NC)           W     = (const float*)d_in[k];
    }
    float* out = (float*)d_out;

    const size_t need = sizeof(float) * (size_t)(NB * NP + NC * NC);
    if (ws_size >= need) {
        float* xxw = (float*)d_ws;                 // 64 KiB
        float* Wt  = (float*)d_ws + NB * NP;       // 64 KiB
        precompute_kernel<<<65, NT, 0, stream>>>(xyz, W, xxw, Wt);
        knn_pool_kernel<true><<<NB * NP, NT, 0, stream>>>(xyz, xxw, feats, out);
        linear_t_kernel<<<NB * NP / LROWS, NT, 0, stream>>>(out, Wt);
    } else {
        knn_pool_kernel<false><<<NB * NP, NT, 0, stream>>>(xyz, nullptr, feats, out);
        linear_kernel<<<NB * NP / 64, NT, 0, stream>>>(out, W);
    }
}